// Round 1
// baseline (634.416 us; speedup 1.0000x reference)
//
#include <hip/hip_runtime.h>
#include <hip/hip_bf16.h>

using bf16x8 = __attribute__((ext_vector_type(8))) __bf16;
using f32x4  = __attribute__((ext_vector_type(4))) float;
typedef unsigned short ushort8v __attribute__((ext_vector_type(8)));
typedef unsigned short ushort4v __attribute__((ext_vector_type(4)));

#define B_ 4
#define C_ 128
#define F_ 128
#define T_ 512
#define H_ 256
#define FT_ 65536
#define M_ 262144

static __device__ __forceinline__ unsigned short bf16bits(float f) {
    __hip_bfloat16 h = __float2bfloat16(f);
    return *(unsigned short*)&h;
}

static __device__ __forceinline__ f32x4 ld4(const __hip_bfloat16* p) {
    ushort4v u = *(const ushort4v*)p;
    f32x4 r;
#pragma unroll
    for (int i = 0; i < 4; ++i) {
        union { unsigned int ui; float f; } cv;
        cv.ui = ((unsigned int)u[i]) << 16;
        r[i] = cv.f;
    }
    return r;
}

static __device__ __forceinline__ f32x4 zero4() {
    f32x4 r = {0.f, 0.f, 0.f, 0.f};
    return r;
}

// ---------------- K0: cast weights to bf16 ----------------
__global__ __launch_bounds__(256) void k_cast(const float* __restrict__ w_in,
                                              const float* __restrict__ w_out,
                                              __hip_bfloat16* __restrict__ wib,
                                              __hip_bfloat16* __restrict__ wob) {
    int i = blockIdx.x * 256 + threadIdx.x;
    if (i < 512 * 128) wib[i] = __float2bfloat16(w_in[i]);
    if (i < 128 * 256) wob[i] = __float2bfloat16(w_out[i]);
}

// ---------------- K1: RMSNorm + transpose to (M, C) bf16 ----------------
// block: one (b,f) row, 128 t's.  grid = B*F*(T/128) = 2048
__global__ __launch_bounds__(256) void k_rms(const float* __restrict__ x,
                                             const float* __restrict__ gn,
                                             __hip_bfloat16* __restrict__ yt) {
    __shared__ float xs[128][129];
    __shared__ float ssqs[2][128];
    __shared__ float scl[128];
    const int bid = blockIdx.x;
    const int tc = bid & 3;
    const int bf = bid >> 2;              // b*F + f
    const int b = bf >> 7, f = bf & 127;
    const int t0 = tc * 128;
    const int th = threadIdx.x;
    const int tl = th & 127, ch = th >> 7;
    const size_t base = (size_t)b * (C_ * FT_) + (size_t)f * T_ + t0;
    float ssq = 0.f;
    for (int c = ch; c < 128; c += 2) {
        float v = x[base + (size_t)c * FT_ + tl];
        xs[c][tl] = v;
        ssq += v * v;
    }
    ssqs[ch][tl] = ssq;
    __syncthreads();
    if (th < 128) {
        float ms = (ssqs[0][th] + ssqs[1][th]) * (1.f / 128.f);
        scl[th] = rsqrtf(ms + 1e-6f);
    }
    __syncthreads();
    const int c = th & 127, tp = th >> 7;
    const float gc = gn[c];
    const size_t m0 = (size_t)bf * T_ + t0;
    for (int tt = 0; tt < 128; tt += 2) {
        const int t = tt + tp;
        float v = xs[c][t] * scl[t] * gc;
        yt[(m0 + t) * 128 + c] = __float2bfloat16(v);
    }
}

// ---------------- K2: GEMM1 (M x 512, K=128) + bias + GLU -> g (M x 256) ----------------
// grid = (M/128, 4); block handles 128 m x 64 g-channels (128 ab-channels).
// B-tile rows n (0..127): q=n>>5, r=n&31; r<16 -> a-channel hb+q*16+r ; r>=16 -> b-channel 256+hb+q*16+(r-16)
// so within a wave, n-fragments alternate a,b,a,b and GLU pairing is same-lane same-reg.
__global__ __launch_bounds__(256) void k_gemm1(const __hip_bfloat16* __restrict__ yt,
                                               const __hip_bfloat16* __restrict__ wib,
                                               const float* __restrict__ b_in,
                                               __hip_bfloat16* __restrict__ gbuf) {
    __shared__ __hip_bfloat16 Al[128][136];
    __shared__ __hip_bfloat16 Bl[128][136];
    const int m0 = blockIdx.x * 128;
    const int hb = blockIdx.y * 64;
    const int th = threadIdx.x;
    {
        const int row = th >> 1, half = th & 1;
        const ushort8v* srcA = (const ushort8v*)(yt + (size_t)(m0 + row) * 128 + half * 64);
        ushort8v* dstA = (ushort8v*)(&Al[row][half * 64]);
#pragma unroll
        for (int i = 0; i < 8; ++i) dstA[i] = srcA[i];
        const int q = row >> 5, r = row & 31;
        const int o = (r < 16) ? (hb + q * 16 + r) : (256 + hb + q * 16 + (r - 16));
        const ushort8v* srcB = (const ushort8v*)(wib + (size_t)o * 128 + half * 64);
        ushort8v* dstB = (ushort8v*)(&Bl[row][half * 64]);
#pragma unroll
        for (int i = 0; i < 8; ++i) dstB[i] = srcB[i];
    }
    __syncthreads();
    const int lane = th & 63, wave = th >> 6;
    const int wm = wave >> 1, wn = wave & 1;
    const int lr = lane & 15, lg = lane >> 4;
    f32x4 acc[4][4] = {};
#pragma unroll
    for (int kk = 0; kk < 4; ++kk) {
        bf16x8 af[4], bq[4];
#pragma unroll
        for (int ma = 0; ma < 4; ++ma)
            af[ma] = *(const bf16x8*)(&Al[wm * 64 + ma * 16 + lr][kk * 32 + lg * 8]);
#pragma unroll
        for (int na = 0; na < 4; ++na)
            bq[na] = *(const bf16x8*)(&Bl[wn * 64 + na * 16 + lr][kk * 32 + lg * 8]);
#pragma unroll
        for (int ma = 0; ma < 4; ++ma)
#pragma unroll
            for (int na = 0; na < 4; ++na)
                acc[ma][na] = __builtin_amdgcn_mfma_f32_16x16x32_bf16(af[ma], bq[na], acc[ma][na], 0, 0, 0);
    }
    __syncthreads();
    // GLU + stage 128x64 bf16 tile into LDS (reuse Bl), then coalesced global write
    __hip_bfloat16 (*gl)[68] = (__hip_bfloat16(*)[68])(&Bl[0][0]);
#pragma unroll
    for (int p = 0; p < 2; ++p) {
        const int q = wn * 2 + p;
        const int oa = hb + q * 16 + lr;
        const float ba = b_in[oa];
        const float bb = b_in[256 + oa];
#pragma unroll
        for (int ma = 0; ma < 4; ++ma) {
            f32x4 va = acc[ma][2 * p];
            f32x4 vb = acc[ma][2 * p + 1];
#pragma unroll
            for (int j = 0; j < 4; ++j) {
                float aa = va[j] + ba;
                float bv = vb[j] + bb;
                float gv = aa / (1.f + __expf(-bv));
                gl[wm * 64 + ma * 16 + lg * 4 + j][wn * 32 + p * 16 + lr] = __float2bfloat16(gv);
            }
        }
    }
    __syncthreads();
#pragma unroll
    for (int pass = 0; pass < 8; ++pass) {
        const int ml = pass * 16 + (th >> 4);
        const int h4 = (th & 15) * 4;
        ushort4v v = *(const ushort4v*)(&gl[ml][h4]);
        *(ushort4v*)((unsigned short*)gbuf + (size_t)(m0 + ml) * 256 + hb + h4) = v;
    }
}

// ---------------- K3: fused dwconv3x3+SiLU (A-tile on the fly) + GEMM2 + bias + residual ----------------
// Operand-swapped MFMA: D[c][m] so stores are t-contiguous per 16 lanes.
// grid = M/128; block computes 128 m x 128 c, K=256 in 2 steps of 128.
__global__ __launch_bounds__(256) void k_gemm2(const __hip_bfloat16* __restrict__ gbuf,
                                               const __hip_bfloat16* __restrict__ wob,
                                               const float* __restrict__ w_dw,
                                               const float* __restrict__ b_dw,
                                               const float* __restrict__ b_out,
                                               const float* __restrict__ x,
                                               float* __restrict__ out) {
    __shared__ __hip_bfloat16 Wl[128][136];
    __shared__ __hip_bfloat16 Sl[128][136];
    const int m0 = blockIdx.x * 128;
    const int th = threadIdx.x;
    const int bfrow = m0 >> 9;            // b*F + f
    const int f = bfrow & 127;
    const int t0 = m0 & 511;
    const int lane = th & 63, wave = th >> 6;
    const int wc = wave >> 1, wn = wave & 1;
    const int lr = lane & 15, lg = lane >> 4;
    const bool hm = (f > 0), hp = (f < 127);
    const __hip_bfloat16* gc_ = gbuf + ((size_t)bfrow * 512) * 256;
    const __hip_bfloat16* gm_ = gc_ - (size_t)512 * 256;
    const __hip_bfloat16* gp_ = gc_ + (size_t)512 * 256;
    f32x4 acc[4][4] = {};
    for (int ks = 0; ks < 2; ++ks) {
        const int o0 = ks * 128;
        {   // stage W tile (128 c x 128 o-slice)
            const int row = th >> 1, half = th & 1;
            const ushort8v* srcW = (const ushort8v*)(wob + (size_t)row * 256 + o0 + half * 64);
            ushort8v* dstW = (ushort8v*)(&Wl[row][half * 64]);
#pragma unroll
            for (int i = 0; i < 8; ++i) dstW[i] = srcW[i];
        }
        {   // compute S tile: dwconv3x3 + b_dw + SiLU, 4 channels/thread, sliding window over t
            const int o4 = o0 + ((th & 31) << 2);
            const int mh8 = th >> 5;              // 0..7, 16 t's each
            const int tb = t0 + mh8 * 16;
            f32x4 wv[9], a0[3], a1[3], a2[3], bias;
#pragma unroll
            for (int i = 0; i < 9; ++i)
#pragma unroll
                for (int c = 0; c < 4; ++c) wv[i][c] = w_dw[(o4 + c) * 9 + i];
#pragma unroll
            for (int c = 0; c < 4; ++c) bias[c] = b_dw[o4 + c];
#pragma unroll
            for (int kI = 0; kI < 2; ++kI) {
                const int t = tb - 2 + kI;
                const bool tv = (t >= 0);
                const size_t off = (size_t)t * 256 + o4;
                a0[kI] = (tv && hm) ? ld4(gm_ + off) : zero4();
                a1[kI] = tv        ? ld4(gc_ + off) : zero4();
                a2[kI] = (tv && hp) ? ld4(gp_ + off) : zero4();
            }
#pragma unroll 4
            for (int k = 0; k < 16; ++k) {
                const int t = tb + k;
                const size_t off = (size_t)t * 256 + o4;
                a0[2] = hm ? ld4(gm_ + off) : zero4();
                a1[2] = ld4(gc_ + off);
                a2[2] = hp ? ld4(gp_ + off) : zero4();
                f32x4 av = bias;
#pragma unroll
                for (int j = 0; j < 3; ++j) {
                    av += wv[j] * a0[j];
                    av += wv[3 + j] * a1[j];
                    av += wv[6 + j] * a2[j];
                }
                ushort4v uo;
#pragma unroll
                for (int c = 0; c < 4; ++c) {
                    float sv = av[c] / (1.f + __expf(-av[c]));
                    uo[c] = bf16bits(sv);
                }
                *(ushort4v*)(&Sl[mh8 * 16 + k][(th & 31) << 2]) = uo;
                a0[0] = a0[1]; a0[1] = a0[2];
                a1[0] = a1[1]; a1[1] = a1[2];
                a2[0] = a2[1]; a2[1] = a2[2];
            }
        }
        __syncthreads();
#pragma unroll
        for (int kk = 0; kk < 4; ++kk) {
            bf16x8 af[4], bq[4];
#pragma unroll
            for (int ca = 0; ca < 4; ++ca)
                af[ca] = *(const bf16x8*)(&Wl[wc * 64 + ca * 16 + lr][kk * 32 + lg * 8]);
#pragma unroll
            for (int na = 0; na < 4; ++na)
                bq[na] = *(const bf16x8*)(&Sl[wn * 64 + na * 16 + lr][kk * 32 + lg * 8]);
#pragma unroll
            for (int ca = 0; ca < 4; ++ca)
#pragma unroll
                for (int na = 0; na < 4; ++na)
                    acc[ca][na] = __builtin_amdgcn_mfma_f32_16x16x32_bf16(af[ca], bq[na], acc[ca][na], 0, 0, 0);
        }
        __syncthreads();
    }
    // epilogue: out[b,c,f,t] = D[c][m] + b_out[c] + x
    const size_t sbase = (size_t)(m0 >> 16) * (C_ * FT_);
#pragma unroll
    for (int ca = 0; ca < 4; ++ca) {
        const int cbase = wc * 64 + ca * 16 + lg * 4;
#pragma unroll
        for (int na = 0; na < 4; ++na) {
            const int m = m0 + wn * 64 + na * 16 + lr;
            const size_t sp = sbase + (size_t)(m & 65535);
#pragma unroll
            for (int j = 0; j < 4; ++j) {
                const int cc = cbase + j;
                const size_t idx = sp + (size_t)cc * FT_;
                out[idx] = acc[ca][na][j] + b_out[cc] + x[idx];
            }
        }
    }
}

extern "C" void kernel_launch(void* const* d_in, const int* in_sizes, int n_in,
                              void* d_out, int out_size, void* d_ws, size_t ws_size,
                              hipStream_t stream) {
    const float* x      = (const float*)d_in[0];
    const float* g_norm = (const float*)d_in[1];
    const float* w_in   = (const float*)d_in[2];
    const float* b_in   = (const float*)d_in[3];
    const float* w_dw   = (const float*)d_in[4];
    const float* b_dw   = (const float*)d_in[5];
    const float* w_out  = (const float*)d_in[6];
    const float* b_out  = (const float*)d_in[7];
    float* out = (float*)d_out;

    // workspace layout (needs ~192.2 MB):
    //   [0, 128MB)            g   : GLU output, (M,256) bf16
    //   [128MB, 192MB)        y_t : rmsnorm output, (M,128) bf16
    //   [192MB, +192KB)       bf16 weights
    char* ws = (char*)d_ws;
    __hip_bfloat16* gbuf = (__hip_bfloat16*)ws;
    __hip_bfloat16* ybuf = (__hip_bfloat16*)(ws + (size_t)134217728);
    __hip_bfloat16* wib  = (__hip_bfloat16*)(ws + (size_t)134217728 + 67108864);
    __hip_bfloat16* wob  = wib + 512 * 128;

    k_cast<<<dim3(256), dim3(256), 0, stream>>>(w_in, w_out, wib, wob);
    k_rms<<<dim3(2048), dim3(256), 0, stream>>>(x, g_norm, ybuf);
    k_gemm1<<<dim3(2048, 4), dim3(256), 0, stream>>>(ybuf, wib, b_in, gbuf);
    k_gemm2<<<dim3(2048), dim3(256), 0, stream>>>(gbuf, wob, w_dw, b_dw, b_out, x, out);
}